// Round 11
// baseline (852.471 us; speedup 1.0000x reference)
//
#include <hip/hip_runtime.h>
#include <hip/hip_bf16.h>

typedef __hip_bfloat16 hb;
typedef short short8 __attribute__((ext_vector_type(8)));
typedef float f32x4 __attribute__((ext_vector_type(4)));
typedef unsigned short u16;

#define NNODE 4096      // per side
#define NEDGE 32768
#define EMB   128
#define ORI   1024
#define SD    20
#define CIN   256       // 2*EMB
#define NCV   3328      // 26*128 (25 spline slots + root slot)
#define LDX   1088      // x operand ld: [x(1024) | aux(64)]
#define LDS_  192       // xs operand ld: [xs(128) | aux(64)]

__device__ __forceinline__ float b2f(hb v){ return __bfloat162float(v); }
__device__ __forceinline__ hb f2b(float v){ return __float2bfloat16(v); }
__device__ __forceinline__ float u2f(u16 u){ hb h; __builtin_memcpy(&h, &u, 2); return b2f(h); }

// split fp32 -> (hi, lo) bf16 pair; x ~= hi + lo with ~2^-18 relative error
__device__ __forceinline__ void split2(float x, u16& hi, u16& lo){
  hb h = f2b(x);
  float r = x - b2f(h);
  hb l = f2b(r);
  __builtin_memcpy(&hi, &h, 2);
  __builtin_memcpy(&lo, &l, 2);
}

// async global->LDS, 16 B per lane. LDS dest is wave-uniform base + lane*16.
__device__ __forceinline__ void gl16(const void* g, void* l){
  __builtin_amdgcn_global_load_lds(
      (const __attribute__((address_space(1))) unsigned int*)(size_t)g,
      (__attribute__((address_space(3))) unsigned int*)(unsigned int)(size_t)l,
      16, 0, 0);
}

// ---------------- prep kernels ----------------

__global__ __launch_bounds__(256) void k_rowsum(const float* __restrict__ Xt, float* __restrict__ rowsum){
  int row = blockIdx.x*4 + (threadIdx.x >> 6);
  int lane = threadIdx.x & 63;
  const float* p = Xt + (size_t)row*512;
  float s = 0.f;
  for (int i = lane; i < 512; i += 64) s += p[i];
  for (int off = 32; off; off >>= 1) s += __shfl_xor(s, off);
  if (lane == 0) rowsum[row] = s;
}

__global__ __launch_bounds__(256) void k_colsum(const float* __restrict__ Xt, float* __restrict__ colsum){
  int col = blockIdx.x*256 + threadIdx.x;     // b*512 + t
  int b = col >> 9, t = col & 511;
  const float* p = Xt + (size_t)b*512*512 + t;
  float s = 0.f;
  for (int sidx = 0; sidx < 512; ++sidx) s += p[(size_t)sidx*512];
  colsum[col] = s;
}

__global__ void k_posemb(const float* __restrict__ vals, int n, float scale, float* __restrict__ out){
  int i = blockIdx.x*blockDim.x + threadIdx.x;
  if (i >= n) return;
  float x = vals[i]*scale;
  float c = -logf(10000.f)/9.f;
  for (int j = 0; j < 10; ++j) {
    float f = expf(c*(float)j);
    out[i*20 + j]      = sinf(x*f);
    out[i*20 + 10 + j] = cosf(x*f);
  }
}

// both sides in one launch; e in [0, 2*NEDGE)
__global__ void k_basis2(const float* __restrict__ ea_s, const float* __restrict__ ea_t,
                         int* __restrict__ idx4, float* __restrict__ w4){
  int e = blockIdx.x*256 + threadIdx.x;
  const float* ea = (e < NEDGE) ? ea_s : ea_t;
  int el = e & (NEDGE-1);
  float p0 = ea[el*2]   * 4.0f;
  float p1 = ea[el*2+1] * 4.0f;
  float l0 = floorf(p0), l1 = floorf(p1);
  float f0 = p0 - l0, f1 = p1 - l1;
  int i0 = (int)l0, i1 = (int)l1;
  int j = 0;
  for (int s1 = 0; s1 <= 1; ++s1)
    for (int s0 = 0; s0 <= 1; ++s0) {
      int a  = min(max(i0 + s0, 0), 4);
      int bb = min(max(i1 + s1, 0), 4);
      float w = (s0 ? f0 : 1.f - f0) * (s1 ? f1 : 1.f - f1);
      idx4[e*4 + j] = a + 5*bb;
      w4[e*4 + j] = w;
      ++j;
    }
}

__global__ void k_count2(const int* __restrict__ ds, const int* __restrict__ dt, int* __restrict__ cnt){
  int e = blockIdx.x*256 + threadIdx.x;     // over 2*NEDGE
  int side = e >= NEDGE;
  int el = e & (NEDGE-1);
  int node = (side ? dt : ds)[el];
  atomicAdd(&cnt[side*NNODE + node], 1);
}

// per-side scan (grid 2); also emits inv-degree
__global__ __launch_bounds__(256) void k_scan2(const int* __restrict__ cntAll, int* __restrict__ rowptrAll,
                                               int* __restrict__ eposAll, float* __restrict__ invAll){
  int sideOff = blockIdx.x*NNODE;
  const int* cnt = cntAll + sideOff;
  int* rowptr = rowptrAll + blockIdx.x*(NNODE+1);
  int* epos = eposAll + sideOff;
  float* inv = invAll + sideOff;
  __shared__ int part[256];
  int tid = threadIdx.x;
  int base = tid*16;
  int v[16]; int s = 0;
  #pragma unroll
  for (int i = 0; i < 16; ++i){
    v[i] = s; int c = cnt[base+i]; s += c;
    inv[base+i] = 1.f / fmaxf((float)c, 1.f);
  }
  part[tid] = s; __syncthreads();
  int total = s;
  for (int off = 1; off < 256; off <<= 1){
    int y = (tid >= off) ? part[tid-off] : 0;
    __syncthreads();
    part[tid] += y;
    __syncthreads();
  }
  int excl = part[tid] - total;
  #pragma unroll
  for (int i = 0; i < 16; ++i){ int r = excl + v[i]; rowptr[base+i] = r; epos[base+i] = r; }
  if (tid == 255) rowptr[4096] = part[255];
}

__global__ void k_fill2(const int* __restrict__ ds, const int* __restrict__ dt,
                        int* __restrict__ eposAll, int* __restrict__ elistAll){
  int e = blockIdx.x*256 + threadIdx.x;     // over 2*NEDGE
  int side = e >= NEDGE;
  int el = e & (NEDGE-1);
  int node = (side ? dt : ds)[el];
  int p = atomicAdd(&eposAll[side*NNODE + node], 1);
  elistAll[side*NEDGE + p] = el;
}

// Xt fp32 -> split bf16: straight (XH/XL) and batch-transposed (TH/TL)
__global__ __launch_bounds__(256) void k_xtT2(const float* __restrict__ Xt,
    u16* __restrict__ XH, u16* __restrict__ XL, u16* __restrict__ TH, u16* __restrict__ TL){
  __shared__ float tile[64][65];
  int b = blockIdx.z, s0 = blockIdx.y*64, t0 = blockIdx.x*64;
  const float* src = Xt + (size_t)b*262144;
  size_t ob = (size_t)b*262144;
  #pragma unroll 4
  for (int p = 0; p < 16; ++p) {
    int idx = p*256 + threadIdx.x;
    int r = idx >> 6, c = idx & 63;
    float v = src[(size_t)(s0+r)*512 + t0 + c];
    tile[r][c] = v;
    size_t o = ob + (size_t)(s0+r)*512 + t0 + c;
    split2(v, XH[o], XL[o]);
  }
  __syncthreads();
  #pragma unroll 4
  for (int p = 0; p < 16; ++p) {
    int idx = p*256 + threadIdx.x;
    int r = idx >> 6, c = idx & 63;   // r: t-local, c: s-local
    float v = tile[c][r];
    size_t o = ob + (size_t)(t0+r)*512 + s0 + c;
    split2(v, TH[o], TL[o]);
  }
}

// weight [Krows][128] fp32 -> split bf16 [128][ldDst], zero-padded cols >= Krows
__global__ void k_wT2(const float* __restrict__ src, u16* __restrict__ dH, u16* __restrict__ dL,
                      int Krows, int ldDst){
  int i = blockIdx.x*256 + threadIdx.x;
  if (i >= 128*ldDst) return;
  int n = i / ldDst, k = i - n*ldDst;
  float v = (k < Krows) ? src[(size_t)k*128 + n] : 0.f;
  split2(v, dH[i], dL[i]);
}

// all 3 layers: conv_w[3][25][256][128] + root[3][256][128] -> split bf16 [3][3328][256]
__global__ void k_wc2(const float* __restrict__ convw, const float* __restrict__ root,
                      u16* __restrict__ dH, u16* __restrict__ dL){
  int i = blockIdx.x*256 + threadIdx.x;   // over 3*3328*256
  int l = i / (NCV*CIN);
  int r = i - l*(NCV*CIN);
  int k = r & 255, n = r >> 8;
  const float* cw = convw + (size_t)l*25*CIN*128;
  const float* rt = root  + (size_t)l*CIN*128;
  float v;
  if (n < 3200) { int kk = n >> 7, col = n & 127; v = cw[((size_t)kk*256 + k)*128 + col]; }
  else          { int col = n & 127;              v = rt[(size_t)k*128 + col]; }
  split2(v, dH[i], dL[i]);
}

// aux = [num(20) | temb(20) | 24 zero pad] per node/side, written as bf16 split
// into the aux columns of xH/xL (cols 1024..1087, ld 1088) and of all three
// xs buffers (cols 128..191, ld 192). aux is layer-invariant.
__global__ void k_aux2(const float* __restrict__ nums, const float* __restrict__ numt,
                       const float* __restrict__ temb,
                       u16* __restrict__ xH, u16* __restrict__ xL,
                       u16* __restrict__ xs0H, u16* __restrict__ xs0L,
                       u16* __restrict__ xs1H, u16* __restrict__ xs1L,
                       u16* __restrict__ xs2H, u16* __restrict__ xs2L){
  int i = blockIdx.x*256 + threadIdx.x;   // over 8192*64
  if (i >= 8192*64) return;
  int r = i >> 6, c = i & 63;
  int side = r >> 12, local = r & 4095, b = (r >> 9) & 7;
  float v = 0.f;
  if (c < 20) v = (side ? numt : nums)[local*20 + c];
  else if (c < 40) v = temb[b*20 + (c - 20)];
  u16 hi, lo; split2(v, hi, lo);
  size_t ox = (size_t)r*LDX + 1024 + c;
  xH[ox] = hi; xL[ox] = lo;
  size_t os = (size_t)r*LDS_ + 128 + c;
  xs0H[os] = hi; xs0L[os] = lo;
  xs1H[os] = hi; xs1L[os] = lo;
  xs2H[os] = hi; xs2L[os] = lo;
}

// generic fp32 -> split bf16 (contiguous)
__global__ __launch_bounds__(256) void k_split(const float* __restrict__ src,
    u16* __restrict__ dH, u16* __restrict__ dL, int n){
  int i = blockIdx.x*256 + threadIdx.x;
  if (i < n) split2(src[i], dH[i], dL[i]);
}

// fp32 [rows][srcW] -> split bf16 at dst stride ldDst (aux cols untouched)
__global__ __launch_bounds__(256) void k_splitW(const float* __restrict__ src,
    u16* __restrict__ dH, u16* __restrict__ dL, int srcW, int ldDst, long dstOff, int n){
  int i = blockIdx.x*256 + threadIdx.x;
  if (i >= n) return;
  int r = i / srcW, c = i - r*srcW;
  size_t o = (size_t)dstOff + (size_t)r*ldDst + c;
  split2(src[i], dH[o], dL[o]);
}

// xin [8192][128] fp32 -> transposed split bf16 [128][8192]; also prefills cat=[xin,xin]
__global__ __launch_bounds__(256) void k_xinT(const float* __restrict__ src,
    u16* __restrict__ dH, u16* __restrict__ dL, float* __restrict__ cat){
  __shared__ float tile[64][65];
  int r0 = blockIdx.x*64, c0 = blockIdx.y*64;
  #pragma unroll 4
  for (int p = 0; p < 16; ++p) {
    int idx = p*256 + threadIdx.x;
    int r = idx >> 6, c = idx & 63;
    float v = src[(size_t)(r0+r)*128 + c0 + c];
    tile[r][c] = v;
    cat[(size_t)(r0+r)*256 + c0 + c]       = v;
    cat[(size_t)(r0+r)*256 + 128 + c0 + c] = v;
  }
  __syncthreads();
  #pragma unroll 4
  for (int p = 0; p < 16; ++p) {
    int idx = p*256 + threadIdx.x;
    int r = idx >> 6, c = idx & 63;   // r: feat-local, c: node-local
    float v = tile[c][r];
    size_t o = (size_t)(c0+r)*8192 + r0 + c;
    split2(v, dH[o], dL[o]);
  }
}

// prefill with bias (8192 rows x 128)
__global__ __launch_bounds__(256) void k_fillbias(const float* __restrict__ b, float* __restrict__ o){
  int i = blockIdx.x*256 + threadIdx.x;   // over 8192*128
  o[i] = b[i & 127];
}

// ---------------- pure-bf16 split-precision MFMA GEMM, double-buffered ----------------
// C[128m x 128n] = A*B with pre-split hi/lo bf16 operands (3 MFMAs per k-frag).
// A [M][K] row-major (lda), B as B^T [N][K] (ldb); K multiple of 32 (zero-padded).
// Staging via global_load_lds width-16, chunk XOR-swizzle on the global address
// (LDS linear). 2-phase pipeline: issue next tile's loads, compute current, ONE
// barrier per K-step -> load latency hides under MFMA.
// grid (mTiles, nTiles, batch*ksplit) — or 2x that in z when A2/B2 given
// (second problem half: blocks with bz >= gridDim.z/2 use A2/B2 and oRowOff2).
// flags: 1 = accumulate; 2 = +bias[col]; 4 = msg epilogue; 8 = atomic split-K;
//        16 = store bf16-hi into (u16*)outF with ld=ldo;
//        32 = XCD-aware block swizzle (requires total blocks % 8 == 0).
__global__ __launch_bounds__(256) void k_gemm(
    const u16* __restrict__ Ah, const u16* __restrict__ Al, int lda, long aBatch,
    const u16* __restrict__ Bh, const u16* __restrict__ Bl, int ldb, long bBatch,
    int K, int flags, int ksplit,
    float* __restrict__ outF, const float* __restrict__ bias,
    int ldo, int oRowOff, int oBatchRows, const float* __restrict__ X,
    const u16* __restrict__ A2h, const u16* __restrict__ A2l,
    const u16* __restrict__ B2h, const u16* __restrict__ B2l, int oRowOff2)
{
  // [buf][plane 0:Ah 1:Al 2:Bh 3:Bl][4096 shorts] = 64 KB total (single array!)
  __shared__ __align__(16) u16 S[2][4][4096];
  const int tid = threadIdx.x;
  const int ln = tid & 63, w = tid >> 6;
  const int wm = (w >> 1)*64, wn = (w & 1)*64;
  const int l15 = ln & 15, q = ln >> 4;
  // block-id derivation, optionally XCD-swizzled (m157: wgid = (orig%8)*(n/8)+orig/8)
  int bxm = blockIdx.x, by = blockIdx.y, bz = blockIdx.z;
  if (flags & 32) {
    int gx = gridDim.x, gy = gridDim.y;
    int n = gx*gy*gridDim.z;
    int bid = (bz*gy + by)*gx + bxm;
    int swz = (bid & 7)*(n >> 3) + (bid >> 3);
    bxm = swz % gx; int rem = swz / gx;
    by = rem % gy; bz = rem / gy;
  }
  const u16* Aph = Ah; const u16* Apl = Al;
  const u16* Bph = Bh; const u16* Bpl = Bl;
  int rowOffSel = oRowOff;
  if (B2h != nullptr) {
    int half = gridDim.z >> 1;
    if (bz >= half) { bz -= half; Aph = A2h; Apl = A2l; Bph = B2h; Bpl = B2l; rowOffSel = oRowOff2; }
  }
  const int batch = bz / ksplit;
  const int kidx  = bz - batch*ksplit;
  const int kSteps = K >> 5;
  const int spc = (kSteps + ksplit - 1) / ksplit;
  const int kBeg = kidx * spc * 32;
  const int kEnd = min(K, kBeg + spc*32);
  if (kBeg >= kEnd) return;
  const u16* Abh = Aph + (size_t)batch*aBatch + (size_t)bxm*128*lda;
  const u16* Abl = Apl + (size_t)batch*aBatch + (size_t)bxm*128*lda;
  const u16* Bbh = Bph + (size_t)batch*bBatch + (size_t)by*128*ldb;
  const u16* Bbl = Bpl + (size_t)batch*bBatch + (size_t)by*128*ldb;

  f32x4 acc[4][4];
  #pragma unroll
  for (int i = 0; i < 4; ++i)
    #pragma unroll
    for (int j = 0; j < 4; ++j) acc[i][j] = (f32x4){0.f,0.f,0.f,0.f};

  // staging geometry: per wave 2 instructions per plane; 16 rows each, 4 lanes/row.
  const int r0 = w*32 + (ln >> 2);
  const int r1 = r0 + 16;
  const int c0 = ((ln & 3) ^ ((r0 >> 1) & 3)) * 8;   // swizzled chunk, in shorts
  const int c1 = ((ln & 3) ^ ((r1 >> 1) & 3)) * 8;

  auto stage = [&](int buf, int kc){
    char* wb = (char*)&S[buf][0][0] + w*2048;
    size_t gA0 = (size_t)r0*lda + kc + c0;
    size_t gA1 = (size_t)r1*lda + kc + c1;
    size_t gB0 = (size_t)r0*ldb + kc + c0;
    size_t gB1 = (size_t)r1*ldb + kc + c1;
    gl16(Abh + gA0, wb);           gl16(Abh + gA1, wb + 1024);
    gl16(Abl + gA0, wb + 8192);    gl16(Abl + gA1, wb + 9216);
    gl16(Bbh + gB0, wb + 16384);   gl16(Bbh + gB1, wb + 17408);
    gl16(Bbl + gB0, wb + 24576);   gl16(Bbl + gB1, wb + 25600);
  };

  auto compute = [&](int buf){
    const u16* AhS = &S[buf][0][0]; const u16* AlS = &S[buf][1][0];
    const u16* BhS = &S[buf][2][0]; const u16* BlS = &S[buf][3][0];
    short8 ah[4], al[4], bh[4], bl[4];
    #pragma unroll
    for (int i = 0; i < 4; ++i) {
      int ra = wm + i*16 + l15;
      int oa = ra*32 + ((q ^ ((ra >> 1) & 3)) << 3);
      ah[i] = *(const short8*)&AhS[oa];
      al[i] = *(const short8*)&AlS[oa];
      int rb = wn + i*16 + l15;
      int ob = rb*32 + ((q ^ ((rb >> 1) & 3)) << 3);
      bh[i] = *(const short8*)&BhS[ob];
      bl[i] = *(const short8*)&BlS[ob];
    }
    #pragma unroll
    for (int i = 0; i < 4; ++i)
      #pragma unroll
      for (int j = 0; j < 4; ++j) {
        acc[i][j] = __builtin_amdgcn_mfma_f32_16x16x32_bf16(ah[i], bl[j], acc[i][j], 0, 0, 0);
        acc[i][j] = __builtin_amdgcn_mfma_f32_16x16x32_bf16(al[i], bh[j], acc[i][j], 0, 0, 0);
        acc[i][j] = __builtin_amdgcn_mfma_f32_16x16x32_bf16(ah[i], bh[j], acc[i][j], 0, 0, 0);
      }
  };

  stage(0, kBeg);
  __syncthreads();
  int cur = 0;
  for (int kc = kBeg; kc < kEnd; kc += 32) {
    if (kc + 32 < kEnd) stage(cur ^ 1, kc + 32);
    compute(cur);
    __syncthreads();
    cur ^= 1;
  }

  const int rowBase = rowOffSel + batch*oBatchRows + bxm*128;
  #pragma unroll
  for (int i = 0; i < 4; ++i) {
    #pragma unroll
    for (int j = 0; j < 4; ++j) {
      int col = by*128 + wn + j*16 + l15;
      #pragma unroll
      for (int r = 0; r < 4; ++r) {
        int row = rowBase + wm + i*16 + q*4 + r;
        float v = acc[i][j][r];
        if (flags & 16) {
          hb hv = f2b(v);
          u16 uv; __builtin_memcpy(&uv, &hv, 2);
          ((u16*)outF)[(size_t)row*ldo + col] = uv;
        } else if (flags & 8) {
          if (flags & 4) unsafeAtomicAdd(&outF[(size_t)row*256 + 128 + col], -v);
          else           unsafeAtomicAdd(&outF[(size_t)row*ldo + col], v);
        } else {
          if (flags & 2) v += bias[col];
          if (flags & 1) v += outF[(size_t)row*ldo + col];
          if (flags & 4) {
            float xv = X[(size_t)row*128 + col];
            outF[(size_t)row*256 + col]       = xv;
            outF[(size_t)row*256 + 128 + col] = xv - v;
          } else {
            outF[(size_t)row*ldo + col] = v;
          }
        }
      }
    }
  }
}

// ---------------- CSR spline gather + root + bias + tanh -> split bf16 out ----------------
// Y is bf16 [2*NNODE][NCV]; both sides in one launch (2 nodes per 256-thread block).
// xs output stride LDS_ (aux columns beyond 128 left untouched).
__global__ __launch_bounds__(256) void k_aggtanh(const u16* __restrict__ Y,
    const int* __restrict__ src_s, const int* __restrict__ src_t,
    const int* __restrict__ elistAll, const int* __restrict__ rowptrAll,
    const int* __restrict__ idx4All, const float* __restrict__ w4All,
    const float* __restrict__ invAll, const float* __restrict__ biasAll, int layer,
    u16* __restrict__ xsH, u16* __restrict__ xsL){
  int n = blockIdx.x*2 + (threadIdx.x >> 7);   // 0..8191 (side-major node index)
  int tid = threadIdx.x & 127;
  int side = n >> 12, local = n & 4095;
  const int* srcarr = side ? src_t : src_s;
  const int* elist  = elistAll + side*NEDGE;
  const int* rowptr = rowptrAll + side*(NNODE+1);
  const int* idx4   = idx4All + (size_t)side*NEDGE*4;
  const float* w4   = w4All + (size_t)side*NEDGE*4;
  const u16* Yb = Y + (size_t)side*NNODE*NCV;
  float acc = u2f(Yb[(size_t)local*NCV + 3200 + tid]);   // root slot (self)
  float wi = invAll[side*NNODE + local];
  int beg = rowptr[local], end = rowptr[local+1];
  for (int p = beg; p < end; ++p) {
    int e = elist[p];
    int sn = srcarr[e];
    const u16* yrow = Yb + (size_t)sn*NCV;
    #pragma unroll
    for (int j = 0; j < 4; ++j) {
      int k = idx4[e*4+j];
      float w = w4[e*4+j]*wi;
      acc += w * u2f(yrow[k*128 + tid]);
    }
  }
  float r = tanhf(acc + biasAll[layer*EMB + tid]);
  split2(r, xsH[(size_t)n*LDS_ + tid], xsL[(size_t)n*LDS_ + tid]);
}

// ---------------- softmax over contiguous fp32 rows of 512 ----------------
__global__ __launch_bounds__(256) void k_softmax(const float* __restrict__ sim, float* __restrict__ out){
  int row = blockIdx.x, tid = threadIdx.x;
  __shared__ float red[8];
  float v0 = sim[(size_t)row*512 + tid];
  float v1 = sim[(size_t)row*512 + 256 + tid];
  int wid = tid >> 6, lane = tid & 63;
  float m = fmaxf(v0, v1);
  for (int off = 32; off; off >>= 1) m = fmaxf(m, __shfl_xor(m, off));
  if (lane == 0) red[wid] = m;
  __syncthreads();
  if (tid == 0) red[4] = fmaxf(fmaxf(red[0], red[1]), fmaxf(red[2], red[3]));
  __syncthreads();
  m = red[4];
  float e0 = expf(v0 - m), e1 = expf(v1 - m);
  float s = e0 + e1;
  for (int off = 32; off; off >>= 1) s += __shfl_xor(s, off);
  if (lane == 0) red[wid] = s;
  __syncthreads();
  if (tid == 0) red[5] = red[0] + red[1] + red[2] + red[3];
  __syncthreads();
  float inv = 1.f / red[5];
  out[(size_t)row*512 + tid]       = e0*inv;
  out[(size_t)row*512 + 256 + tid] = e1*inv;
}

// ---------------- host ----------------

extern "C" void kernel_launch(void* const* d_in, const int* in_sizes, int n_in,
                              void* d_out, int out_size, void* d_ws, size_t ws_size,
                              hipStream_t stream){
  (void)in_sizes; (void)n_in; (void)out_size; (void)ws_size;
  const float* t_in      = (const float*)d_in[0];
  const float* Xt        = (const float*)d_in[1];
  const float* x_s       = (const float*)d_in[2];
  const float* x_t       = (const float*)d_in[3];
  const float* ea_s      = (const float*)d_in[4];
  const float* ea_t      = (const float*)d_in[5];
  const float* lin0_w    = (const float*)d_in[6];
  const float* lin0_b    = (const float*)d_in[7];
  const float* lin_w     = (const float*)d_in[8];
  const float* lin_b     = (const float*)d_in[9];
  const float* conv_w    = (const float*)d_in[10];
  const float* conv_root = (const float*)d_in[11];
  const float* conv_bias = (const float*)d_in[12];
  const float* final_w   = (const float*)d_in[13];
  const float* final_b   = (const float*)d_in[14];
  const int*   ei_s      = (const int*)d_in[15];
  const int*   ei_t      = (const int*)d_in[16];
  float* out = (float*)d_out;

  char* wsb = (char*)d_ws;
  size_t off = 0;
  auto alloc = [&](size_t bytes)->char*{
    char* p = wsb + off;
    off += (bytes + 255) & ~(size_t)255;
    return p;
  };
  float* f_sums  = (float*)alloc(8192*4);             // rowsum | colsum
  float* f_temb  = (float*)alloc(8*SD*4);
  float* f_num   = (float*)alloc((size_t)8192*SD*4);  // num_s | num_t
  int*   i_idx   = (int*)  alloc((size_t)2*NEDGE*4*4);
  float* f_w     = (float*)alloc((size_t)2*NEDGE*4*4);
  int*   i_cnt   = (int*)  alloc((size_t)2*NNODE*4);
  float* f_inv   = (float*)alloc((size_t)2*NNODE*4);
  int*   i_rp    = (int*)  alloc((size_t)2*(NNODE+1)*4);
  int*   i_ep    = (int*)  alloc((size_t)2*NNODE*4);
  int*   i_el    = (int*)  alloc((size_t)2*NEDGE*4);
  // split bf16 operand buffers
  u16* XtH  = (u16*)alloc((size_t)8*512*512*2);     // 4.2 MB each
  u16* XtL  = (u16*)alloc((size_t)8*512*512*2);
  u16* XtTH = (u16*)alloc((size_t)8*512*512*2);
  u16* XtTL = (u16*)alloc((size_t)8*512*512*2);
  u16* w0H  = (u16*)alloc((size_t)128*1088*2);
  u16* w0L  = (u16*)alloc((size_t)128*1088*2);
  u16* w1H  = (u16*)alloc((size_t)128*192*2);
  u16* w1L  = (u16*)alloc((size_t)128*192*2);
  u16* w2H  = (u16*)alloc((size_t)128*192*2);
  u16* w2L  = (u16*)alloc((size_t)128*192*2);
  u16* wfH  = (u16*)alloc((size_t)128*1408*2);
  u16* wfL  = (u16*)alloc((size_t)128*1408*2);
  u16* wcH  = (u16*)alloc((size_t)3*NCV*CIN*2);     // 5.1 MB each
  u16* wcL  = (u16*)alloc((size_t)3*NCV*CIN*2);
  u16* xH   = (u16*)alloc((size_t)8192*LDX*2);      // 17.8 MB each ([x|aux])
  u16* xL   = (u16*)alloc((size_t)8192*LDX*2);
  u16* xsH[3]; u16* xsL[3];
  for (int l = 0; l < 3; ++l) {
    xsH[l] = (u16*)alloc((size_t)8192*LDS_*2);      // 3.1 MB each ([xs|aux])
    xsL[l] = (u16*)alloc((size_t)8192*LDS_*2);
  }
  u16* catH = (u16*)alloc((size_t)8192*CIN*2);      // 4.2 MB each
  u16* catL = (u16*)alloc((size_t)8192*CIN*2);
  float* f_xin = (float*)alloc((size_t)8192*EMB*4); // 4.2 MB; reused as h
  float* f_cat = (float*)alloc((size_t)8192*CIN*4); // 8.4 MB
  // Y (bf16, both sides) = 8192*3328*2 = 54.5 MB; sim (fp32 8.4 MB) aliases its start
  u16*   f_Y   = (u16*)  alloc((size_t)8192*NCV*2);
  float* f_sim = (float*)f_Y;                       // disjoint lifetimes
  // aliased into f_Y tail (lifetimes disjoint from Y contents):
  u16* xiTH = (u16*)((char*)f_Y + (size_t)20*1024*1024);  // live only between k_xinT and msg GEMMs
  u16* xiTL = (u16*)((char*)f_Y + (size_t)23*1024*1024);
  u16* hH   = (u16*)((char*)f_Y + (size_t)26*1024*1024);  // live only after all layers
  u16* hL   = (u16*)((char*)f_Y + (size_t)29*1024*1024);

  auto gemm = [&](const u16* Ahp, const u16* Alp, int lda, long aB,
                  const u16* Bhp, const u16* Blp, int ldb, long bB,
                  int K, int flags, int ksplit, float* o, const float* bias,
                  int ldo, int rowOff, int oBR, const float* X, dim3 grid,
                  const u16* A2h = nullptr, const u16* A2l = nullptr,
                  const u16* B2h = nullptr, const u16* B2l = nullptr, int rowOff2 = 0){
    k_gemm<<<grid, 256, 0, stream>>>(Ahp, Alp, lda, aB, Bhp, Blp, ldb, bB, K, flags, ksplit,
                                     o, bias, ldo, rowOff, oBR, X,
                                     A2h, A2l, B2h, B2l, rowOff2);
  };

  // --- prep ---
  k_xtT2<<<dim3(8,8,8), 256, 0, stream>>>(Xt, XtH, XtL, XtTH, XtTL);
  k_rowsum<<<NNODE/4, 256, 0, stream>>>(Xt, f_sums);
  k_colsum<<<NNODE/256, 256, 0, stream>>>(Xt, f_sums + NNODE);
  k_posemb<<<8192/256, 256, 0, stream>>>(f_sums, 8192, 0.1f, f_num);
  k_posemb<<<1, 64, 0, stream>>>(t_in, 8, 1.0f, f_temb);
  k_aux2<<<(8192*64)/256, 256, 0, stream>>>(f_num, f_num + (size_t)NNODE*SD, f_temb,
      xH, xL, xsH[0], xsL[0], xsH[1], xsL[1], xsH[2], xsL[2]);
  k_basis2<<<2*NEDGE/256, 256, 0, stream>>>(ea_s, ea_t, i_idx, f_w);
  hipMemsetAsync(i_cnt, 0, 2*NNODE*4, stream);
  k_count2<<<2*NEDGE/256, 256, 0, stream>>>(ei_s + NEDGE, ei_t + NEDGE, i_cnt);
  k_scan2<<<2, 256, 0, stream>>>(i_cnt, i_rp, i_ep, f_inv);
  k_fill2<<<2*NEDGE/256, 256, 0, stream>>>(ei_s + NEDGE, ei_t + NEDGE, i_ep, i_el);
  k_wT2<<<(128*1088)/256, 256, 0, stream>>>(lin0_w, w0H, w0L, 1064, 1088);
  k_wT2<<<(128*192)/256, 256, 0, stream>>>(lin_w, w1H, w1L, 168, 192);
  k_wT2<<<(128*192)/256, 256, 0, stream>>>(lin_w + (size_t)168*128, w2H, w2L, 168, 192);
  k_wT2<<<(128*1408)/256, 256, 0, stream>>>(final_w, wfH, wfL, 1408, 1408);
  k_wc2<<<(3*NCV*CIN)/256, 256, 0, stream>>>(conv_w, conv_root, wcH, wcL);
  k_splitW<<<(4096*1024)/256, 256, 0, stream>>>(x_s, xH, xL, 1024, LDX, 0, 4096*1024);
  k_splitW<<<(4096*1024)/256, 256, 0, stream>>>(x_t, xH, xL, 1024, LDX, (long)4096*LDX, 4096*1024);

  for (int i = 0; i < 3; ++i) {
    const u16* wTh = (i == 0) ? w0H : (i == 1) ? w1H : w2H;
    const u16* wTl = (i == 0) ? w0L : (i == 1) ? w1L : w2L;
    const float* bv = (i == 0) ? lin0_b : lin_b + (i-1)*EMB;
    int ldw = (i == 0) ? 1088 : 192;

    // lin: xin = [x|num|temb] @ W + b — bias prefill + ONE atomic split-K GEMM
    // (A operand has aux columns folded in; K covers the full padded width).
    k_fillbias<<<4096, 256, 0, stream>>>(bv, f_xin);
    const u16* A0h = (i == 0) ? xH : xsH[i-1];
    const u16* A0l = (i == 0) ? xL : xsL[i-1];
    int lda = (i == 0) ? LDX : LDS_;
    int Kf  = (i == 0) ? LDX : LDS_;
    int ks  = (i == 0) ? 8 : 6;
    gemm(A0h, A0l, lda, 0, wTh, wTl, ldw, 0,
         Kf, 8|32, ks, f_xin, nullptr, EMB, 0, 0, nullptr, dim3(64,1,ks));

    // transpose-split xin for msg B operand; also prefill cat with [xin, xin]
    k_xinT<<<dim3(128,2), 256, 0, stream>>>(f_xin, xiTH, xiTL, f_cat);
    // msg (batched over b), both sides in ONE dispatch (z-halves), split-K atomic
    // subtract into second half of cat.
    gemm(XtH, XtL, 512, 262144, xiTH + 4096, xiTL + 4096, 8192, 512,
         512, 4|8|32, 8, f_cat, nullptr, 256, 0, 512, nullptr, dim3(4,1,128),
         XtTH, XtTL, xiTH, xiTL, NNODE);
    k_split<<<(8192*CIN)/256, 256, 0, stream>>>(f_cat, catH, catL, 8192*CIN);

    // spline conv, BOTH sides in one dispatch (z-halves, B shared):
    // Y[side*NNODE + m][n] (bf16) = cat_side @ [W_0..W_24|root], XCD-swizzled
    gemm(catH, catL, CIN, 0,
         wcH + (size_t)i*NCV*CIN, wcL + (size_t)i*NCV*CIN, CIN, 0,
         CIN, 16|32, 1, (float*)f_Y, nullptr, NCV, 0, 0, nullptr, dim3(32,26,2),
         catH + (size_t)NNODE*CIN, catL + (size_t)NNODE*CIN,
         wcH + (size_t)i*NCV*CIN, wcL + (size_t)i*NCV*CIN, NNODE);
    // CSR gather + tanh, both sides in one dispatch
    k_aggtanh<<<4096, 256, 0, stream>>>(f_Y, ei_s, ei_t, i_el, i_rp,
        i_idx, f_w, f_inv, conv_bias, i, xsH[i], xsL[i]);
  }

  // final projection -> h (reuse f_xin): prefill bias, then 4 atomic split-K passes
  float* f_h = f_xin;
  k_fillbias<<<4096, 256, 0, stream>>>(final_b, f_h);
  gemm(xH, xL, LDX, 0, wfH, wfL, 1408, 0,
       1024, 8|32, 8, f_h, nullptr, EMB, 0, 0, nullptr, dim3(64,1,8));
  for (int l = 0; l < 3; ++l)
    gemm(xsH[l], xsL[l], LDS_, 0, wfH + 1024 + l*128, wfL + 1024 + l*128, 1408, 0,
         128, 8|32, 4, f_h, nullptr, EMB, 0, 0, nullptr, dim3(64,1,4));
  k_split<<<(8192*EMB)/256, 256, 0, stream>>>(f_h, hH, hL, 8192*EMB);

  // sim[4096,512] = hs @ ht^T (batched over b), split-K=4 atomic for occupancy
  hipMemsetAsync(f_sim, 0, (size_t)4096*512*4, stream);
  gemm(hH, hL, EMB, 65536, hH + (size_t)4096*EMB, hL + (size_t)4096*EMB, EMB, 65536,
       EMB, 8|32, 4, f_sim, nullptr, 512, 0, 512, nullptr, dim3(4,4,32));

  k_softmax<<<NNODE, 256, 0, stream>>>(f_sim, out);
}

// Round 12
// 785.877 us; speedup vs baseline: 1.0847x; 1.0847x over previous
//
#include <hip/hip_runtime.h>
#include <hip/hip_bf16.h>

typedef __hip_bfloat16 hb;
typedef short short8 __attribute__((ext_vector_type(8)));
typedef float f32x4 __attribute__((ext_vector_type(4)));
typedef unsigned short u16;

#define NNODE 4096      // per side
#define NEDGE 32768
#define EMB   128
#define ORI   1024
#define SD    20
#define CIN   256       // 2*EMB
#define NCV   3328      // 26*128 (25 spline slots + root slot)
#define LDX   1088      // x operand ld: [x(1024) | aux(64)]
#define XSW   576       // combined xs operand ld: 3 x [xs(128) | aux(64)]

__device__ __forceinline__ float b2f(hb v){ return __bfloat162float(v); }
__device__ __forceinline__ hb f2b(float v){ return __float2bfloat16(v); }
__device__ __forceinline__ float u2f(u16 u){ hb h; __builtin_memcpy(&h, &u, 2); return b2f(h); }

// split fp32 -> (hi, lo) bf16 pair; x ~= hi + lo with ~2^-18 relative error
__device__ __forceinline__ void split2(float x, u16& hi, u16& lo){
  hb h = f2b(x);
  float r = x - b2f(h);
  hb l = f2b(r);
  __builtin_memcpy(&hi, &h, 2);
  __builtin_memcpy(&lo, &l, 2);
}

// async global->LDS, 16 B per lane. LDS dest is wave-uniform base + lane*16.
__device__ __forceinline__ void gl16(const void* g, void* l){
  __builtin_amdgcn_global_load_lds(
      (const __attribute__((address_space(1))) unsigned int*)(size_t)g,
      (__attribute__((address_space(3))) unsigned int*)(unsigned int)(size_t)l,
      16, 0, 0);
}

// posemb frequency j (0..9)
__device__ __forceinline__ float pefreq(int j){
  return expf((-logf(10000.f)/9.f)*(float)j);
}

// ---------------- prep kernels ----------------

// rowsum (blocks 0..1023, 4 rows each) + colsum (blocks 1024..1039)
__global__ __launch_bounds__(256) void k_rc(const float* __restrict__ Xt, float* __restrict__ sums){
  if (blockIdx.x < 1024) {
    int row = blockIdx.x*4 + (threadIdx.x >> 6);
    int lane = threadIdx.x & 63;
    const float* p = Xt + (size_t)row*512;
    float s = 0.f;
    for (int i = lane; i < 512; i += 64) s += p[i];
    for (int off = 32; off; off >>= 1) s += __shfl_xor(s, off);
    if (lane == 0) sums[row] = s;
  } else {
    int col = (blockIdx.x - 1024)*256 + threadIdx.x;  // b*512 + t
    int b = col >> 9, t = col & 511;
    const float* p = Xt + (size_t)b*512*512 + t;
    float s = 0.f;
    for (int sidx = 0; sidx < 512; ++sidx) s += p[(size_t)sidx*512];
    sums[NNODE + col] = s;
  }
}

// spline basis + degree count, both sides, one launch over 2*NEDGE
__global__ void k_bc(const float* __restrict__ ea_s, const float* __restrict__ ea_t,
                     const int* __restrict__ ds, const int* __restrict__ dt,
                     int* __restrict__ idx4, float* __restrict__ w4, int* __restrict__ cnt){
  int e = blockIdx.x*256 + threadIdx.x;
  int side = e >= NEDGE;
  int el = e & (NEDGE-1);
  const float* ea = side ? ea_t : ea_s;
  float p0 = ea[el*2]   * 4.0f;
  float p1 = ea[el*2+1] * 4.0f;
  float l0 = floorf(p0), l1 = floorf(p1);
  float f0 = p0 - l0, f1 = p1 - l1;
  int i0 = (int)l0, i1 = (int)l1;
  int j = 0;
  for (int s1 = 0; s1 <= 1; ++s1)
    for (int s0 = 0; s0 <= 1; ++s0) {
      int a  = min(max(i0 + s0, 0), 4);
      int bb = min(max(i1 + s1, 0), 4);
      float w = (s0 ? f0 : 1.f - f0) * (s1 ? f1 : 1.f - f1);
      idx4[e*4 + j] = a + 5*bb;
      w4[e*4 + j] = w;
      ++j;
    }
  int node = (side ? dt : ds)[el];
  atomicAdd(&cnt[side*NNODE + node], 1);
}

// per-side scan (grid 2); also emits inv-degree
__global__ __launch_bounds__(256) void k_scan2(const int* __restrict__ cntAll, int* __restrict__ rowptrAll,
                                               int* __restrict__ eposAll, float* __restrict__ invAll){
  int sideOff = blockIdx.x*NNODE;
  const int* cnt = cntAll + sideOff;
  int* rowptr = rowptrAll + blockIdx.x*(NNODE+1);
  int* epos = eposAll + sideOff;
  float* inv = invAll + sideOff;
  __shared__ int part[256];
  int tid = threadIdx.x;
  int base = tid*16;
  int v[16]; int s = 0;
  #pragma unroll
  for (int i = 0; i < 16; ++i){
    v[i] = s; int c = cnt[base+i]; s += c;
    inv[base+i] = 1.f / fmaxf((float)c, 1.f);
  }
  part[tid] = s; __syncthreads();
  int total = s;
  for (int off = 1; off < 256; off <<= 1){
    int y = (tid >= off) ? part[tid-off] : 0;
    __syncthreads();
    part[tid] += y;
    __syncthreads();
  }
  int excl = part[tid] - total;
  #pragma unroll
  for (int i = 0; i < 16; ++i){ int r = excl + v[i]; rowptr[base+i] = r; epos[base+i] = r; }
  if (tid == 255) rowptr[4096] = part[255];
}

__global__ void k_fill2(const int* __restrict__ ds, const int* __restrict__ dt,
                        int* __restrict__ eposAll, int* __restrict__ elistAll){
  int e = blockIdx.x*256 + threadIdx.x;     // over 2*NEDGE
  int side = e >= NEDGE;
  int el = e & (NEDGE-1);
  int node = (side ? dt : ds)[el];
  int p = atomicAdd(&eposAll[side*NNODE + node], 1);
  elistAll[side*NEDGE + p] = el;
}

// Xt fp32 -> split bf16: straight (XH/XL) and batch-transposed (TH/TL)
__global__ __launch_bounds__(256) void k_xtT2(const float* __restrict__ Xt,
    u16* __restrict__ XH, u16* __restrict__ XL, u16* __restrict__ TH, u16* __restrict__ TL){
  __shared__ float tile[64][65];
  int b = blockIdx.z, s0 = blockIdx.y*64, t0 = blockIdx.x*64;
  const float* src = Xt + (size_t)b*262144;
  size_t ob = (size_t)b*262144;
  #pragma unroll 4
  for (int p = 0; p < 16; ++p) {
    int idx = p*256 + threadIdx.x;
    int r = idx >> 6, c = idx & 63;
    float v = src[(size_t)(s0+r)*512 + t0 + c];
    tile[r][c] = v;
    size_t o = ob + (size_t)(s0+r)*512 + t0 + c;
    split2(v, XH[o], XL[o]);
  }
  __syncthreads();
  #pragma unroll 4
  for (int p = 0; p < 16; ++p) {
    int idx = p*256 + threadIdx.x;
    int r = idx >> 6, c = idx & 63;   // r: t-local, c: s-local
    float v = tile[c][r];
    size_t o = ob + (size_t)(t0+r)*512 + s0 + c;
    split2(v, TH[o], TL[o]);
  }
}

// all weight transposes in one launch (range-dispatched):
// w0 [128][1088] <- lin0_w(1064x128); w1/w2 [128][192] <- lin_w layers (168x128);
// wf [128][1408] <- final_w; wf3 [128][576] <- final_w rows 1024.. with zeroed aux-K rows.
#define SEG0 139264   // 128*1088
#define SEG1 163840   // +128*192
#define SEG2 188416   // +128*192
#define SEG3 368640   // +128*1408
#define SEG4 442368   // +128*576
__global__ __launch_bounds__(256) void k_wprep(const float* __restrict__ lin0_w,
    const float* __restrict__ lin_w, const float* __restrict__ final_w,
    u16* __restrict__ w0H, u16* __restrict__ w0L,
    u16* __restrict__ w1H, u16* __restrict__ w1L,
    u16* __restrict__ w2H, u16* __restrict__ w2L,
    u16* __restrict__ wfH, u16* __restrict__ wfL,
    u16* __restrict__ wf3H, u16* __restrict__ wf3L){
  int i = blockIdx.x*256 + threadIdx.x;
  float v; u16 *dH, *dL; int e;
  if (i < SEG0) {
    e = i; int n = e/1088, k = e - n*1088;
    v = (k < 1064) ? lin0_w[(size_t)k*128 + n] : 0.f;
    dH = w0H; dL = w0L;
  } else if (i < SEG1) {
    e = i - SEG0; int n = e/192, k = e - n*192;
    v = (k < 168) ? lin_w[(size_t)k*128 + n] : 0.f;
    dH = w1H; dL = w1L;
  } else if (i < SEG2) {
    e = i - SEG1; int n = e/192, k = e - n*192;
    v = (k < 168) ? lin_w[(size_t)(168 + k)*128 + n] : 0.f;
    dH = w2H; dL = w2L;
  } else if (i < SEG3) {
    e = i - SEG2; int n = e/1408, k = e - n*1408;
    v = final_w[(size_t)k*128 + n];
    dH = wfH; dL = wfL;
  } else {
    e = i - SEG3; int n = e/576, k = e - n*576;
    int l = k/192, kk = k - l*192;
    v = (kk < 128) ? final_w[(size_t)(1024 + l*128 + kk)*128 + n] : 0.f;
    dH = wf3H; dL = wf3L;
  }
  split2(v, dH[e], dL[e]);
}

// all 3 layers: conv_w[3][25][256][128] + root[3][256][128] -> split bf16 [3][3328][256]
__global__ void k_wc2(const float* __restrict__ convw, const float* __restrict__ root,
                      u16* __restrict__ dH, u16* __restrict__ dL){
  int i = blockIdx.x*256 + threadIdx.x;   // over 3*3328*256
  int l = i / (NCV*CIN);
  int r = i - l*(NCV*CIN);
  int k = r & 255, n = r >> 8;
  const float* cw = convw + (size_t)l*25*CIN*128;
  const float* rt = root  + (size_t)l*CIN*128;
  float v;
  if (n < 3200) { int kk = n >> 7, col = n & 127; v = cw[((size_t)kk*256 + k)*128 + col]; }
  else          { int col = n & 127;              v = rt[(size_t)k*128 + col]; }
  split2(v, dH[i], dL[i]);
}

// aux = [num(20) | temb(20) | 24 zero pad] per node/side, computed INLINE from
// f_sums (row/col sums) and t_in; written as bf16 split into the aux columns of
// xH/xL (cols 1024..1087, ld 1088) and of all three xs slots of the combined
// xs buffer (cols l*192+128 .. l*192+191, ld 576). aux is layer-invariant.
__global__ void k_aux2(const float* __restrict__ sums, const float* __restrict__ t_in,
                       u16* __restrict__ xH, u16* __restrict__ xL,
                       u16* __restrict__ xsAllH, u16* __restrict__ xsAllL){
  int i = blockIdx.x*256 + threadIdx.x;   // over 8192*64
  if (i >= 8192*64) return;
  int r = i >> 6, c = i & 63;
  int side = r >> 12, local = r & 4095, b = (r >> 9) & 7;
  float v = 0.f;
  if (c < 20) {
    float x = sums[side*NNODE + local] * 0.1f;
    v = (c < 10) ? sinf(x*pefreq(c)) : cosf(x*pefreq(c-10));
  } else if (c < 40) {
    float x = t_in[b];
    int cc = c - 20;
    v = (cc < 10) ? sinf(x*pefreq(cc)) : cosf(x*pefreq(cc-10));
  }
  u16 hi, lo; split2(v, hi, lo);
  size_t ox = (size_t)r*LDX + 1024 + c;
  xH[ox] = hi; xL[ox] = lo;
  #pragma unroll
  for (int l = 0; l < 3; ++l) {
    size_t os = (size_t)r*XSW + l*192 + 128 + c;
    xsAllH[os] = hi; xsAllL[os] = lo;
  }
}

// generic fp32 -> split bf16 (contiguous)
__global__ __launch_bounds__(256) void k_split(const float* __restrict__ src,
    u16* __restrict__ dH, u16* __restrict__ dL, int n){
  int i = blockIdx.x*256 + threadIdx.x;
  if (i < n) split2(src[i], dH[i], dL[i]);
}

// fp32 [rows][srcW] -> split bf16 at dst stride ldDst (aux cols untouched)
__global__ __launch_bounds__(256) void k_splitW(const float* __restrict__ src,
    u16* __restrict__ dH, u16* __restrict__ dL, int srcW, int ldDst, long dstOff, int n){
  int i = blockIdx.x*256 + threadIdx.x;
  if (i >= n) return;
  int r = i / srcW, c = i - r*srcW;
  size_t o = (size_t)dstOff + (size_t)r*ldDst + c;
  split2(src[i], dH[o], dL[o]);
}

// xin [8192][128] fp32 -> transposed split bf16 [128][8192]; also prefills cat=[xin,xin]
__global__ __launch_bounds__(256) void k_xinT(const float* __restrict__ src,
    u16* __restrict__ dH, u16* __restrict__ dL, float* __restrict__ cat){
  __shared__ float tile[64][65];
  int r0 = blockIdx.x*64, c0 = blockIdx.y*64;
  #pragma unroll 4
  for (int p = 0; p < 16; ++p) {
    int idx = p*256 + threadIdx.x;
    int r = idx >> 6, c = idx & 63;
    float v = src[(size_t)(r0+r)*128 + c0 + c];
    tile[r][c] = v;
    cat[(size_t)(r0+r)*256 + c0 + c]       = v;
    cat[(size_t)(r0+r)*256 + 128 + c0 + c] = v;
  }
  __syncthreads();
  #pragma unroll 4
  for (int p = 0; p < 16; ++p) {
    int idx = p*256 + threadIdx.x;
    int r = idx >> 6, c = idx & 63;   // r: feat-local, c: node-local
    float v = tile[c][r];
    size_t o = (size_t)(c0+r)*8192 + r0 + c;
    split2(v, dH[o], dL[o]);
  }
}

// prefill with bias (8192 rows x 128)
__global__ __launch_bounds__(256) void k_fillbias(const float* __restrict__ b, float* __restrict__ o){
  int i = blockIdx.x*256 + threadIdx.x;   // over 8192*128
  o[i] = b[i & 127];
}

// ---------------- pure-bf16 split-precision MFMA GEMM, double-buffered ----------------
// C[128m x 128n] = A*B with pre-split hi/lo bf16 operands (3 MFMAs per k-frag).
// A [M][K] row-major (lda), B as B^T [N][K] (ldb); K multiple of 32 (zero-padded).
// Staging via global_load_lds width-16, chunk XOR-swizzle on the global address
// (LDS linear). 2-phase pipeline: issue next tile's loads, compute current, ONE
// barrier per K-step -> load latency hides under MFMA.
// grid (mTiles, nTiles, batch*ksplit) — or 2x that in z when A2/B2 given.
// flags: 1 = accumulate; 2 = +bias[col]; 4 = msg epilogue; 8 = atomic split-K;
//        16 = store bf16-hi into (u16*)outF with ld=ldo.
__global__ __launch_bounds__(256) void k_gemm(
    const u16* __restrict__ Ah, const u16* __restrict__ Al, int lda, long aBatch,
    const u16* __restrict__ Bh, const u16* __restrict__ Bl, int ldb, long bBatch,
    int K, int flags, int ksplit,
    float* __restrict__ outF, const float* __restrict__ bias,
    int ldo, int oRowOff, int oBatchRows, const float* __restrict__ X,
    const u16* __restrict__ A2h, const u16* __restrict__ A2l,
    const u16* __restrict__ B2h, const u16* __restrict__ B2l, int oRowOff2)
{
  // [buf][plane 0:Ah 1:Al 2:Bh 3:Bl][4096 shorts] = 64 KB total (single array!)
  __shared__ __align__(16) u16 S[2][4][4096];
  const int tid = threadIdx.x;
  const int ln = tid & 63, w = tid >> 6;
  const int wm = (w >> 1)*64, wn = (w & 1)*64;
  const int l15 = ln & 15, q = ln >> 4;
  int bxm = blockIdx.x, by = blockIdx.y, bz = blockIdx.z;
  const u16* Aph = Ah; const u16* Apl = Al;
  const u16* Bph = Bh; const u16* Bpl = Bl;
  int rowOffSel = oRowOff;
  if (B2h != nullptr) {
    int half = gridDim.z >> 1;
    if (bz >= half) { bz -= half; Aph = A2h; Apl = A2l; Bph = B2h; Bpl = B2l; rowOffSel = oRowOff2; }
  }
  const int batch = bz / ksplit;
  const int kidx  = bz - batch*ksplit;
  const int kSteps = K >> 5;
  const int spc = (kSteps + ksplit - 1) / ksplit;
  const int kBeg = kidx * spc * 32;
  const int kEnd = min(K, kBeg + spc*32);
  if (kBeg >= kEnd) return;
  const u16* Abh = Aph + (size_t)batch*aBatch + (size_t)bxm*128*lda;
  const u16* Abl = Apl + (size_t)batch*aBatch + (size_t)bxm*128*lda;
  const u16* Bbh = Bph + (size_t)batch*bBatch + (size_t)by*128*ldb;
  const u16* Bbl = Bpl + (size_t)batch*bBatch + (size_t)by*128*ldb;

  f32x4 acc[4][4];
  #pragma unroll
  for (int i = 0; i < 4; ++i)
    #pragma unroll
    for (int j = 0; j < 4; ++j) acc[i][j] = (f32x4){0.f,0.f,0.f,0.f};

  // staging geometry: per wave 2 instructions per plane; 16 rows each, 4 lanes/row.
  const int r0 = w*32 + (ln >> 2);
  const int r1 = r0 + 16;
  const int c0 = ((ln & 3) ^ ((r0 >> 1) & 3)) * 8;   // swizzled chunk, in shorts
  const int c1 = ((ln & 3) ^ ((r1 >> 1) & 3)) * 8;

  auto stage = [&](int buf, int kc){
    char* wb = (char*)&S[buf][0][0] + w*2048;
    size_t gA0 = (size_t)r0*lda + kc + c0;
    size_t gA1 = (size_t)r1*lda + kc + c1;
    size_t gB0 = (size_t)r0*ldb + kc + c0;
    size_t gB1 = (size_t)r1*ldb + kc + c1;
    gl16(Abh + gA0, wb);           gl16(Abh + gA1, wb + 1024);
    gl16(Abl + gA0, wb + 8192);    gl16(Abl + gA1, wb + 9216);
    gl16(Bbh + gB0, wb + 16384);   gl16(Bbh + gB1, wb + 17408);
    gl16(Bbl + gB0, wb + 24576);   gl16(Bbl + gB1, wb + 25600);
  };

  auto compute = [&](int buf){
    const u16* AhS = &S[buf][0][0]; const u16* AlS = &S[buf][1][0];
    const u16* BhS = &S[buf][2][0]; const u16* BlS = &S[buf][3][0];
    short8 ah[4], al[4], bh[4], bl[4];
    #pragma unroll
    for (int i = 0; i < 4; ++i) {
      int ra = wm + i*16 + l15;
      int oa = ra*32 + ((q ^ ((ra >> 1) & 3)) << 3);
      ah[i] = *(const short8*)&AhS[oa];
      al[i] = *(const short8*)&AlS[oa];
      int rb = wn + i*16 + l15;
      int ob = rb*32 + ((q ^ ((rb >> 1) & 3)) << 3);
      bh[i] = *(const short8*)&BhS[ob];
      bl[i] = *(const short8*)&BlS[ob];
    }
    #pragma unroll
    for (int i = 0; i < 4; ++i)
      #pragma unroll
      for (int j = 0; j < 4; ++j) {
        acc[i][j] = __builtin_amdgcn_mfma_f32_16x16x32_bf16(ah[i], bl[j], acc[i][j], 0, 0, 0);
        acc[i][j] = __builtin_amdgcn_mfma_f32_16x16x32_bf16(al[i], bh[j], acc[i][j], 0, 0, 0);
        acc[i][j] = __builtin_amdgcn_mfma_f32_16x16x32_bf16(ah[i], bh[j], acc[i][j], 0, 0, 0);
      }
  };

  stage(0, kBeg);
  __syncthreads();
  int cur = 0;
  for (int kc = kBeg; kc < kEnd; kc += 32) {
    if (kc + 32 < kEnd) stage(cur ^ 1, kc + 32);
    compute(cur);
    __syncthreads();
    cur ^= 1;
  }

  const int rowBase = rowOffSel + batch*oBatchRows + bxm*128;
  #pragma unroll
  for (int i = 0; i < 4; ++i) {
    #pragma unroll
    for (int j = 0; j < 4; ++j) {
      int col = by*128 + wn + j*16 + l15;
      #pragma unroll
      for (int r = 0; r < 4; ++r) {
        int row = rowBase + wm + i*16 + q*4 + r;
        float v = acc[i][j][r];
        if (flags & 16) {
          hb hv = f2b(v);
          u16 uv; __builtin_memcpy(&uv, &hv, 2);
          ((u16*)outF)[(size_t)row*ldo + col] = uv;
        } else if (flags & 8) {
          if (flags & 4) unsafeAtomicAdd(&outF[(size_t)row*256 + 128 + col], -v);
          else           unsafeAtomicAdd(&outF[(size_t)row*ldo + col], v);
        } else {
          if (flags & 2) v += bias[col];
          if (flags & 1) v += outF[(size_t)row*ldo + col];
          if (flags & 4) {
            float xv = X[(size_t)row*128 + col];
            outF[(size_t)row*256 + col]       = xv;
            outF[(size_t)row*256 + 128 + col] = xv - v;
          } else {
            outF[(size_t)row*ldo + col] = v;
          }
        }
      }
    }
  }
}

// ---------------- CSR spline gather + root + bias + tanh -> split bf16 out ----------------
// Y is bf16 [2*NNODE][NCV]; both sides in one launch (2 nodes per 256-thread block).
// xs output stride XSW (576); xsH/xsL already offset to this layer's column slot.
__global__ __launch_bounds__(256) void k_aggtanh(const u16* __restrict__ Y,
    const int* __restrict__ src_s, const int* __restrict__ src_t,
    const int* __restrict__ elistAll, const int* __restrict__ rowptrAll,
    const int* __restrict__ idx4All, const float* __restrict__ w4All,
    const float* __restrict__ invAll, const float* __restrict__ biasAll, int layer,
    u16* __restrict__ xsH, u16* __restrict__ xsL){
  int n = blockIdx.x*2 + (threadIdx.x >> 7);   // 0..8191 (side-major node index)
  int tid = threadIdx.x & 127;
  int side = n >> 12, local = n & 4095;
  const int* srcarr = side ? src_t : src_s;
  const int* elist  = elistAll + side*NEDGE;
  const int* rowptr = rowptrAll + side*(NNODE+1);
  const int* idx4   = idx4All + (size_t)side*NEDGE*4;
  const float* w4   = w4All + (size_t)side*NEDGE*4;
  const u16* Yb = Y + (size_t)side*NNODE*NCV;
  float acc = u2f(Yb[(size_t)local*NCV + 3200 + tid]);   // root slot (self)
  float wi = invAll[side*NNODE + local];
  int beg = rowptr[local], end = rowptr[local+1];
  for (int p = beg; p < end; ++p) {
    int e = elist[p];
    int sn = srcarr[e];
    const u16* yrow = Yb + (size_t)sn*NCV;
    #pragma unroll
    for (int j = 0; j < 4; ++j) {
      int k = idx4[e*4+j];
      float w = w4[e*4+j]*wi;
      acc += w * u2f(yrow[k*128 + tid]);
    }
  }
  float r = tanhf(acc + biasAll[layer*EMB + tid]);
  split2(r, xsH[(size_t)n*XSW + tid], xsL[(size_t)n*XSW + tid]);
}

// ---------------- softmax over contiguous fp32 rows of 512 ----------------
__global__ __launch_bounds__(256) void k_softmax(const float* __restrict__ sim, float* __restrict__ out){
  int row = blockIdx.x, tid = threadIdx.x;
  __shared__ float red[8];
  float v0 = sim[(size_t)row*512 + tid];
  float v1 = sim[(size_t)row*512 + 256 + tid];
  int wid = tid >> 6, lane = tid & 63;
  float m = fmaxf(v0, v1);
  for (int off = 32; off; off >>= 1) m = fmaxf(m, __shfl_xor(m, off));
  if (lane == 0) red[wid] = m;
  __syncthreads();
  if (tid == 0) red[4] = fmaxf(fmaxf(red[0], red[1]), fmaxf(red[2], red[3]));
  __syncthreads();
  m = red[4];
  float e0 = expf(v0 - m), e1 = expf(v1 - m);
  float s = e0 + e1;
  for (int off = 32; off; off >>= 1) s += __shfl_xor(s, off);
  if (lane == 0) red[wid] = s;
  __syncthreads();
  if (tid == 0) red[5] = red[0] + red[1] + red[2] + red[3];
  __syncthreads();
  float inv = 1.f / red[5];
  out[(size_t)row*512 + tid]       = e0*inv;
  out[(size_t)row*512 + 256 + tid] = e1*inv;
}

// ---------------- host ----------------

extern "C" void kernel_launch(void* const* d_in, const int* in_sizes, int n_in,
                              void* d_out, int out_size, void* d_ws, size_t ws_size,
                              hipStream_t stream){
  (void)in_sizes; (void)n_in; (void)out_size; (void)ws_size;
  const float* t_in      = (const float*)d_in[0];
  const float* Xt        = (const float*)d_in[1];
  const float* x_s       = (const float*)d_in[2];
  const float* x_t       = (const float*)d_in[3];
  const float* ea_s      = (const float*)d_in[4];
  const float* ea_t      = (const float*)d_in[5];
  const float* lin0_w    = (const float*)d_in[6];
  const float* lin0_b    = (const float*)d_in[7];
  const float* lin_w     = (const float*)d_in[8];
  const float* lin_b     = (const float*)d_in[9];
  const float* conv_w    = (const float*)d_in[10];
  const float* conv_root = (const float*)d_in[11];
  const float* conv_bias = (const float*)d_in[12];
  const float* final_w   = (const float*)d_in[13];
  const float* final_b   = (const float*)d_in[14];
  const int*   ei_s      = (const int*)d_in[15];
  const int*   ei_t      = (const int*)d_in[16];
  float* out = (float*)d_out;

  char* wsb = (char*)d_ws;
  size_t off = 0;
  auto alloc = [&](size_t bytes)->char*{
    char* p = wsb + off;
    off += (bytes + 255) & ~(size_t)255;
    return p;
  };
  float* f_sums  = (float*)alloc(8192*4);             // rowsum | colsum
  int*   i_idx   = (int*)  alloc((size_t)2*NEDGE*4*4);
  float* f_w     = (float*)alloc((size_t)2*NEDGE*4*4);
  int*   i_cnt   = (int*)  alloc((size_t)2*NNODE*4);
  float* f_inv   = (float*)alloc((size_t)2*NNODE*4);
  int*   i_rp    = (int*)  alloc((size_t)2*(NNODE+1)*4);
  int*   i_ep    = (int*)  alloc((size_t)2*NNODE*4);
  int*   i_el    = (int*)  alloc((size_t)2*NEDGE*4);
  // split bf16 operand buffers
  u16* XtH  = (u16*)alloc((size_t)8*512*512*2);     // 4.2 MB each
  u16* XtL  = (u16*)alloc((size_t)8*512*512*2);
  u16* XtTH = (u16*)alloc((size_t)8*512*512*2);
  u16* XtTL = (u16*)alloc((size_t)8*512*512*2);
  u16* w0H  = (u16*)alloc((size_t)128*1088*2);
  u16* w0L  = (u16*)alloc((size_t)128*1088*2);
  u16* w1H  = (u16*)alloc((size_t)128*192*2);
  u16* w1L  = (u16*)alloc((size_t)128*192*2);
  u16* w2H  = (u16*)alloc((size_t)128*192*2);
  u16* w2L  = (u16*)alloc((size_t)128*192*2);
  u16* wfH  = (u16*)alloc((size_t)128*1408*2);
  u16* wfL  = (u16*)alloc((size_t)128*1408*2);
  u16* wf3H = (u16*)alloc((size_t)128*576*2);
  u16* wf3L = (u16*)alloc((size_t)128*576*2);
  u16* wcH  = (u16*)alloc((size_t)3*NCV*CIN*2);     // 5.1 MB each
  u16* wcL  = (u16*)alloc((size_t)3*NCV*CIN*2);
  u16* xH   = (u16*)alloc((size_t)8192*LDX*2);      // 17.8 MB each ([x|aux])
  u16* xL   = (u16*)alloc((size_t)8192*LDX*2);
  u16* xsAllH = (u16*)alloc((size_t)8192*XSW*2);    // 9.4 MB each (3 x [xs|aux])
  u16* xsAllL = (u16*)alloc((size_t)8192*XSW*2);
  u16* catH = (u16*)alloc((size_t)8192*CIN*2);      // 4.2 MB each
  u16* catL = (u16*)alloc((size_t)8192*CIN*2);
  float* f_xin = (float*)alloc((size_t)8192*EMB*4); // 4.2 MB; reused as h
  float* f_cat = (float*)alloc((size_t)8192*CIN*4); // 8.4 MB
  // Y (bf16, both sides) = 8192*3328*2 = 54.5 MB; sim (fp32 8.4 MB) aliases its start
  u16*   f_Y   = (u16*)  alloc((size_t)8192*NCV*2);
  float* f_sim = (float*)f_Y;                       // disjoint lifetimes
  // aliased into f_Y tail (lifetimes disjoint from Y contents):
  u16* xiTH = (u16*)((char*)f_Y + (size_t)20*1024*1024);  // live only between k_xinT and msg GEMMs
  u16* xiTL = (u16*)((char*)f_Y + (size_t)23*1024*1024);
  u16* hH   = (u16*)((char*)f_Y + (size_t)26*1024*1024);  // live only after all layers
  u16* hL   = (u16*)((char*)f_Y + (size_t)29*1024*1024);

  auto gemm = [&](const u16* Ahp, const u16* Alp, int lda, long aB,
                  const u16* Bhp, const u16* Blp, int ldb, long bB,
                  int K, int flags, int ksplit, float* o, const float* bias,
                  int ldo, int rowOff, int oBR, const float* X, dim3 grid,
                  const u16* A2h = nullptr, const u16* A2l = nullptr,
                  const u16* B2h = nullptr, const u16* B2l = nullptr, int rowOff2 = 0){
    k_gemm<<<grid, 256, 0, stream>>>(Ahp, Alp, lda, aB, Bhp, Blp, ldb, bB, K, flags, ksplit,
                                     o, bias, ldo, rowOff, oBR, X,
                                     A2h, A2l, B2h, B2l, rowOff2);
  };

  // --- prep ---
  k_xtT2<<<dim3(8,8,8), 256, 0, stream>>>(Xt, XtH, XtL, XtTH, XtTL);
  k_rc<<<1040, 256, 0, stream>>>(Xt, f_sums);
  k_aux2<<<(8192*64)/256, 256, 0, stream>>>(f_sums, t_in, xH, xL, xsAllH, xsAllL);
  hipMemsetAsync(i_cnt, 0, 2*NNODE*4, stream);
  k_bc<<<2*NEDGE/256, 256, 0, stream>>>(ea_s, ea_t, ei_s + NEDGE, ei_t + NEDGE,
                                        i_idx, f_w, i_cnt);
  k_scan2<<<2, 256, 0, stream>>>(i_cnt, i_rp, i_ep, f_inv);
  k_fill2<<<2*NEDGE/256, 256, 0, stream>>>(ei_s + NEDGE, ei_t + NEDGE, i_ep, i_el);
  k_wprep<<<SEG4/256, 256, 0, stream>>>(lin0_w, lin_w, final_w,
      w0H, w0L, w1H, w1L, w2H, w2L, wfH, wfL, wf3H, wf3L);
  k_wc2<<<(3*NCV*CIN)/256, 256, 0, stream>>>(conv_w, conv_root, wcH, wcL);
  k_splitW<<<(4096*1024)/256, 256, 0, stream>>>(x_s, xH, xL, 1024, LDX, 0, 4096*1024);
  k_splitW<<<(4096*1024)/256, 256, 0, stream>>>(x_t, xH, xL, 1024, LDX, (long)4096*LDX, 4096*1024);

  for (int i = 0; i < 3; ++i) {
    const u16* wTh = (i == 0) ? w0H : (i == 1) ? w1H : w2H;
    const u16* wTl = (i == 0) ? w0L : (i == 1) ? w1L : w2L;
    const float* bv = (i == 0) ? lin0_b : lin_b + (i-1)*EMB;
    int ldw = (i == 0) ? 1088 : 192;

    // lin: xin = [x|num|temb] @ W + b — bias prefill + ONE atomic split-K GEMM
    k_fillbias<<<4096, 256, 0, stream>>>(bv, f_xin);
    const u16* A0h = (i == 0) ? xH : xsAllH + (i-1)*192;
    const u16* A0l = (i == 0) ? xL : xsAllL + (i-1)*192;
    int lda = (i == 0) ? LDX : XSW;
    int Kf  = (i == 0) ? LDX : 192;
    int ks  = (i == 0) ? 8 : 6;
    gemm(A0h, A0l, lda, 0, wTh, wTl, ldw, 0,
         Kf, 8, ks, f_xin, nullptr, EMB, 0, 0, nullptr, dim3(64,1,ks));

    // transpose-split xin for msg B operand; also prefill cat with [xin, xin]
    k_xinT<<<dim3(128,2), 256, 0, stream>>>(f_xin, xiTH, xiTL, f_cat);
    // msg (batched over b), both sides in ONE dispatch (z-halves), split-K atomic
    // subtract into second half of cat.
    gemm(XtH, XtL, 512, 262144, xiTH + 4096, xiTL + 4096, 8192, 512,
         512, 4|8, 8, f_cat, nullptr, 256, 0, 512, nullptr, dim3(4,1,128),
         XtTH, XtTL, xiTH, xiTL, NNODE);
    k_split<<<(8192*CIN)/256, 256, 0, stream>>>(f_cat, catH, catL, 8192*CIN);

    // spline conv, BOTH sides in one dispatch (z-halves, B shared):
    // Y[side*NNODE + m][n] (bf16) = cat_side @ [W_0..W_24|root]
    gemm(catH, catL, CIN, 0,
         wcH + (size_t)i*NCV*CIN, wcL + (size_t)i*NCV*CIN, CIN, 0,
         CIN, 16, 1, (float*)f_Y, nullptr, NCV, 0, 0, nullptr, dim3(32,26,2),
         catH + (size_t)NNODE*CIN, catL + (size_t)NNODE*CIN,
         wcH + (size_t)i*NCV*CIN, wcL + (size_t)i*NCV*CIN, NNODE);
    // CSR gather + tanh, both sides in one dispatch; writes this layer's xs slot
    k_aggtanh<<<4096, 256, 0, stream>>>(f_Y, ei_s, ei_t, i_el, i_rp,
        i_idx, f_w, f_inv, conv_bias, i, xsAllH + i*192, xsAllL + i*192);
  }

  // final projection -> h (reuse f_xin): prefill bias, then ORI pass + ONE merged
  // xs pass (K=576 across all 3 layers; wf3 has zeroed aux-K rows)
  float* f_h = f_xin;
  k_fillbias<<<4096, 256, 0, stream>>>(final_b, f_h);
  gemm(xH, xL, LDX, 0, wfH, wfL, 1408, 0,
       1024, 8, 8, f_h, nullptr, EMB, 0, 0, nullptr, dim3(64,1,8));
  gemm(xsAllH, xsAllL, XSW, 0, wf3H, wf3L, 576, 0,
       576, 8, 6, f_h, nullptr, EMB, 0, 0, nullptr, dim3(64,1,6));
  k_split<<<(8192*EMB)/256, 256, 0, stream>>>(f_h, hH, hL, 8192*EMB);

  // sim[4096,512] = hs @ ht^T (batched over b), split-K=4 atomic for occupancy
  hipMemsetAsync(f_sim, 0, (size_t)4096*512*4, stream);
  gemm(hH, hL, EMB, 65536, hH + (size_t)4096*EMB, hL + (size_t)4096*EMB, EMB, 65536,
       EMB, 8, 4, f_sim, nullptr, 512, 0, 512, nullptr, dim3(4,4,32));

  k_softmax<<<NNODE, 256, 0, stream>>>(f_sim, out);
}